// Round 3
// baseline (924.607 us; speedup 1.0000x reference)
//
#include <hip/hip_runtime.h>
#include <hip/hip_bf16.h>
#include <cmath>

// Problem dims (fixed by reference): B=2, T=2048, C=1024, H=16, D=64
// Inputs fp32, output fp32 (reference returns fp32).
#define TB   2048
#define CCH  1024
#define NH   16
#define DDIM 64
#define NCH  32      // chunks per (b,h): T / 64
#define EPSF 1e-6f

// ---------------------------------------------------------------------------
// GEMM1: qkv = phi(x @ w_attn) for q,k thirds (cols < 2048), identity for v.
// A: (4096,1024) fp32 row-major; B: (1024,3072) fp32 row-major; C: fp32.
// 64x64 tile, 256 threads, 4x4 microtile, fp32 accumulate.
// ---------------------------------------------------------------------------
__global__ __launch_bounds__(256) void gemm_qkv_k(
    const float* __restrict__ A,
    const float* __restrict__ B,
    float* __restrict__ C)
{
    const int N = 3072, K = 1024;
    __shared__ float As[16][65];
    __shared__ float Bs[16][65];
    const int tx = threadIdx.x & 15, ty = threadIdx.x >> 4;
    const int row0 = blockIdx.y * 64, col0 = blockIdx.x * 64;
    float acc[4][4] = {};
    for (int k0 = 0; k0 < K; k0 += 16) {
        for (int e = threadIdx.x; e < 1024; e += 256) {
            int m = e >> 4, kk = e & 15;
            As[kk][m] = A[(size_t)(row0 + m) * K + k0 + kk];
        }
        for (int e = threadIdx.x; e < 1024; e += 256) {
            int kk = e >> 6, n = e & 63;
            Bs[kk][n] = B[(size_t)(k0 + kk) * N + col0 + n];
        }
        __syncthreads();
        #pragma unroll
        for (int kk = 0; kk < 16; ++kk) {
            float a[4], b[4];
            #pragma unroll
            for (int i = 0; i < 4; ++i) a[i] = As[kk][ty * 4 + i];
            #pragma unroll
            for (int j = 0; j < 4; ++j) b[j] = Bs[kk][tx * 4 + j];
            #pragma unroll
            for (int i = 0; i < 4; ++i)
                #pragma unroll
                for (int j = 0; j < 4; ++j)
                    acc[i][j] += a[i] * b[j];
        }
        __syncthreads();
    }
    #pragma unroll
    for (int i = 0; i < 4; ++i) {
        int m = row0 + ty * 4 + i;
        #pragma unroll
        for (int j = 0; j < 4; ++j) {
            int n = col0 + tx * 4 + j;
            float v = acc[i][j];
            if (n < 2 * CCH) v = (v > 0.f) ? (v + 1.f) : __expf(v);  // phi = elu+1
            C[(size_t)m * N + n] = v;
        }
    }
}

// ---------------------------------------------------------------------------
// Per-chunk local state: S_c = K_c^T V_c (64x64), z_c = sum_s k_s.
// Grid: (b*H + h)*NCH + c  -> 1024 blocks, 256 threads.
// ---------------------------------------------------------------------------
__global__ __launch_bounds__(256) void chunk_kv_k(
    const float* __restrict__ qkv,
    float* __restrict__ Sloc,
    float* __restrict__ zloc)
{
    __shared__ float Ks[64][64];
    __shared__ float Vs[64][64];
    const int blk = blockIdx.x;
    const int c = blk & 31, h = (blk >> 5) & 15, b = blk >> 9;
    const int t0 = c * 64;
    for (int e = threadIdx.x; e < 4096; e += 256) {
        int s = e >> 6, d = e & 63;
        size_t row = (size_t)(b * TB + t0 + s) * 3072;
        Ks[s][d] = qkv[row + 1024 + h * 64 + d];
        Vs[s][d] = qkv[row + 2048 + h * 64 + d];
    }
    __syncthreads();
    const int i = threadIdx.x >> 2;            // 0..63 (k-feature)
    const int j0 = (threadIdx.x & 3) << 4;     // v-feature group of 16
    float acc[16] = {};
    for (int s = 0; s < 64; ++s) {
        float kv = Ks[s][i];
        #pragma unroll
        for (int j = 0; j < 16; ++j) acc[j] += kv * Vs[s][j0 + j];
    }
    float* So = Sloc + (size_t)blk * 4096;
    #pragma unroll
    for (int j = 0; j < 16; ++j) So[i * 64 + j0 + j] = acc[j];
    if (threadIdx.x < 64) {
        float z = 0.f;
        for (int s = 0; s < 64; ++s) z += Ks[s][threadIdx.x];
        zloc[(size_t)blk * 64 + threadIdx.x] = z;
    }
}

// ---------------------------------------------------------------------------
// Exclusive prefix over chunk axis, elementwise (every state element is an
// independent 32-long scan). Grid: 32 (b,h) * 8 parts = 256 blocks.
// ---------------------------------------------------------------------------
__global__ __launch_bounds__(256) void scan_state_k(
    float* __restrict__ S, float* __restrict__ z)
{
    const int bh = blockIdx.x >> 3;
    const int part = blockIdx.x & 7;
    const int e0 = part * 512 + threadIdx.x;   // this thread owns e0 and e0+256
    const size_t base = (size_t)bh * NCH * 4096;
    float r0 = 0.f, r1 = 0.f;
    for (int c = 0; c < NCH; ++c) {
        float* Sc = S + base + (size_t)c * 4096;
        float t0 = Sc[e0];       Sc[e0] = r0;       r0 += t0;
        float t1 = Sc[e0 + 256]; Sc[e0 + 256] = r1; r1 += t1;
    }
    if (part == 0 && threadIdx.x < 64) {
        const size_t zb = (size_t)bh * NCH * 64;
        float rz = 0.f;
        for (int c = 0; c < NCH; ++c) {
            float t = z[zb + c * 64 + threadIdx.x];
            z[zb + c * 64 + threadIdx.x] = rz;
            rz += t;
        }
    }
}

// ---------------------------------------------------------------------------
// Per-chunk output: y = (Q @ S_pref + causal(Q K^T) @ V) / (q.z_pref + rowsum + eps)
// LDS buffer Ps is reused: S_pref -> K -> A. 1024 blocks, 256 threads.
// Thread (t = tid/4, j0 = (tid%4)*16) owns 16 output features of row t.
// ---------------------------------------------------------------------------
__global__ __launch_bounds__(256) void chunk_attn_k(
    const float* __restrict__ qkv,
    const float* __restrict__ Spref,
    const float* __restrict__ zpref,
    float* __restrict__ Y)
{
    __shared__ float Qs[64][64];
    __shared__ float Ps[64][65];   // reused: Sp, then K, then A
    __shared__ float Vs[64][64];
    __shared__ float zps[64];

    const int blk = blockIdx.x;
    const int c = blk & 31, h = (blk >> 5) & 15, b = blk >> 9;
    const int t0 = c * 64;
    const float* Sblk = Spref + (size_t)blk * 4096;

    for (int e = threadIdx.x; e < 4096; e += 256) {
        int s = e >> 6, d = e & 63;
        size_t row = (size_t)(b * TB + t0 + s) * 3072;
        Qs[s][d] = qkv[row + h * 64 + d];
        Vs[s][d] = qkv[row + 2048 + h * 64 + d];
        Ps[s][d] = Sblk[e];        // Ps[d][j] = S_pref[d][j]
    }
    if (threadIdx.x < 64) zps[threadIdx.x] = zpref[(size_t)blk * 64 + threadIdx.x];
    __syncthreads();

    const int t = threadIdx.x >> 2;
    const int j0 = (threadIdx.x & 3) << 4;

    // Inter-chunk part: y = Q[t,:] @ S_pref ; den = Q[t,:].z_pref
    float y[16] = {};
    float den = 0.f;
    for (int d = 0; d < 64; ++d) {
        float qd = Qs[t][d];
        den += qd * zps[d];
        #pragma unroll
        for (int j = 0; j < 16; ++j) y[j] += qd * Ps[d][j0 + j];
    }
    __syncthreads();

    // Load K into Ps
    for (int e = threadIdx.x; e < 4096; e += 256) {
        int s = e >> 6, d = e & 63;
        size_t row = (size_t)(b * TB + t0 + s) * 3072;
        Ps[s][d] = qkv[row + 1024 + h * 64 + d];
    }
    __syncthreads();

    // A[t][s0..s0+15] = Q[t,:].K[s,:], causal-masked
    float areg[16] = {};
    const int s0 = j0;
    for (int d = 0; d < 64; ++d) {
        float qd = Qs[t][d];
        #pragma unroll
        for (int j = 0; j < 16; ++j) areg[j] += qd * Ps[s0 + j][d];
    }
    #pragma unroll
    for (int j = 0; j < 16; ++j) if (s0 + j > t) areg[j] = 0.f;
    __syncthreads();

    // Write A into Ps
    #pragma unroll
    for (int j = 0; j < 16; ++j) Ps[t][s0 + j] = areg[j];
    __syncthreads();

    // Intra-chunk part: y += A[t,:] @ V ; den += rowsum(A[t,:])
    float rowsum = 0.f;
    for (int s = 0; s < 64; ++s) {
        float a = Ps[t][s];
        rowsum += a;
        #pragma unroll
        for (int j = 0; j < 16; ++j) y[j] += a * Vs[s][j0 + j];
    }
    den += rowsum;
    const float inv = 1.f / (den + EPSF);
    const size_t orow = (size_t)(b * TB + t0 + t) * CCH + h * 64 + j0;
    #pragma unroll
    for (int j = 0; j < 16; ++j) Y[orow + j] = y[j] * inv;
}

// ---------------------------------------------------------------------------
// GEMM2: out = Y @ w_proj. A: (4096,1024) fp32; B: (1024,1024) fp32; out fp32.
// ---------------------------------------------------------------------------
__global__ __launch_bounds__(256) void gemm_proj_k(
    const float* __restrict__ A,
    const float* __restrict__ B,
    float* __restrict__ C)
{
    const int N = 1024, K = 1024;
    __shared__ float As[16][65];
    __shared__ float Bs[16][65];
    const int tx = threadIdx.x & 15, ty = threadIdx.x >> 4;
    const int row0 = blockIdx.y * 64, col0 = blockIdx.x * 64;
    float acc[4][4] = {};
    for (int k0 = 0; k0 < K; k0 += 16) {
        for (int e = threadIdx.x; e < 1024; e += 256) {
            int m = e >> 4, kk = e & 15;
            As[kk][m] = A[(size_t)(row0 + m) * K + k0 + kk];
        }
        for (int e = threadIdx.x; e < 1024; e += 256) {
            int kk = e >> 6, n = e & 63;
            Bs[kk][n] = B[(size_t)(k0 + kk) * N + col0 + n];
        }
        __syncthreads();
        #pragma unroll
        for (int kk = 0; kk < 16; ++kk) {
            float a[4], b[4];
            #pragma unroll
            for (int i = 0; i < 4; ++i) a[i] = As[kk][ty * 4 + i];
            #pragma unroll
            for (int j = 0; j < 4; ++j) b[j] = Bs[kk][tx * 4 + j];
            #pragma unroll
            for (int i = 0; i < 4; ++i)
                #pragma unroll
                for (int j = 0; j < 4; ++j)
                    acc[i][j] += a[i] * b[j];
        }
        __syncthreads();
    }
    #pragma unroll
    for (int i = 0; i < 4; ++i) {
        int m = row0 + ty * 4 + i;
        #pragma unroll
        for (int j = 0; j < 4; ++j) {
            int n = col0 + tx * 4 + j;
            C[(size_t)m * N + n] = acc[i][j];
        }
    }
}

// ---------------------------------------------------------------------------
extern "C" void kernel_launch(void* const* d_in, const int* in_sizes, int n_in,
                              void* d_out, int out_size, void* d_ws, size_t ws_size,
                              hipStream_t stream)
{
    const float* x      = (const float*)d_in[0]; // (2,2048,1024) fp32
    const float* w_attn = (const float*)d_in[1]; // (1024,3072)   fp32
    const float* w_proj = (const float*)d_in[2]; // (1024,1024)   fp32
    float* out = (float*)d_out;                  // (2,2048,1024) fp32

    // Workspace layout (fp32):
    //   qkv  : 4096*3072             = 12,582,912 f
    //   Sloc : 2*16*32*4096          =  4,194,304 f
    //   zloc : 2*16*32*64            =     65,536 f
    //   Y    : 4096*1024             =  4,194,304 f
    // total ~84.2 MB
    float* ws   = (float*)d_ws;
    float* qkv  = ws;
    float* Sloc = qkv  + (size_t)4096 * 3072;
    float* zloc = Sloc + (size_t)1024 * 4096;
    float* Yw   = zloc + (size_t)1024 * 64;

    gemm_qkv_k <<<dim3(48, 64), 256, 0, stream>>>(x, w_attn, qkv);
    chunk_kv_k <<<1024,         256, 0, stream>>>(qkv, Sloc, zloc);
    scan_state_k<<<256,         256, 0, stream>>>(Sloc, zloc);
    chunk_attn_k<<<1024,        256, 0, stream>>>(qkv, Sloc, zloc, Yw);
    gemm_proj_k<<<dim3(16, 64), 256, 0, stream>>>(Yw, w_proj, out);
}

// Round 4
// 263.470 us; speedup vs baseline: 3.5093x; 3.5093x over previous
//
#include <hip/hip_runtime.h>
#include <hip/hip_bf16.h>
#include <cmath>

// Problem dims (fixed by reference): B=2, T=2048, C=1024, H=16, D=64
// Inputs fp32, output fp32.
#define TB   2048
#define CCH  1024
#define NCH  32      // chunks per (b,h): T / 64
#define EPSF 1e-6f

typedef unsigned short u16;
typedef __attribute__((ext_vector_type(8))) short  frag8;   // 8 bf16 (4 VGPRs)
typedef __attribute__((ext_vector_type(4))) float  floatx4; // MFMA C/D

// RNE float -> bf16 (finite inputs only)
__device__ __forceinline__ u16 f2bf(float f) {
    unsigned int u = __float_as_uint(f);
    unsigned int r = (u + 0x7fffu + ((u >> 16) & 1u)) >> 16;
    return (u16)r;
}

// ---------------------------------------------------------------------------
// Convert fp32 -> bf16, 8 elems/thread (n multiple of 2048*8 here).
// ---------------------------------------------------------------------------
__global__ __launch_bounds__(256) void cvt_bf16_k(
    const float* __restrict__ in, u16* __restrict__ out, int n)
{
    int i = (blockIdx.x * 256 + threadIdx.x) * 8;
    if (i >= n) return;
    float4 a = *(const float4*)(in + i);
    float4 b = *(const float4*)(in + i + 4);
    u16 v[8];
    v[0] = f2bf(a.x); v[1] = f2bf(a.y); v[2] = f2bf(a.z); v[3] = f2bf(a.w);
    v[4] = f2bf(b.x); v[5] = f2bf(b.y); v[6] = f2bf(b.z); v[7] = f2bf(b.w);
    *(uint4*)(out + i) = *(uint4*)v;
}

// ---------------------------------------------------------------------------
// Transpose + convert: in (K x N fp32, row-major) -> out (N x K bf16).
// 64x64 tile, 256 threads.
// ---------------------------------------------------------------------------
__global__ __launch_bounds__(256) void transpose_bf16_k(
    const float* __restrict__ in, u16* __restrict__ out, int K, int N)
{
    __shared__ u16 t[64][65];
    const int k0 = blockIdx.y * 64, n0 = blockIdx.x * 64;
    const int c = threadIdx.x & 63, r0 = threadIdx.x >> 6;
    for (int r = r0; r < 64; r += 4)
        t[c][r] = f2bf(in[(size_t)(k0 + r) * N + n0 + c]);
    __syncthreads();
    for (int r = r0; r < 64; r += 4)
        out[(size_t)(n0 + r) * K + k0 + c] = t[r][c];
}

// ---------------------------------------------------------------------------
// bf16 MFMA GEMM: C(MxN fp32) = A(MxK bf16 row-major) * BT(NxK bf16)^T
// phi (elu+1) applied to columns < phi_cols.
// 128x128 tile, BK=64, 256 threads = 4 waves, each wave 64x64 (4x4 frags).
// ---------------------------------------------------------------------------
__global__ __launch_bounds__(256) void gemm_bf16_k(
    const u16* __restrict__ A, const u16* __restrict__ BT,
    float* __restrict__ C, int N, int K, int phi_cols)
{
    __shared__ u16 Als[128][72];   // +8 pad: 16B-aligned rows, conflict-free frags
    __shared__ u16 Bls[128][72];
    const int tid  = threadIdx.x;
    const int wave = tid >> 6, lane = tid & 63;
    const int quad = lane >> 4, lrow = lane & 15;
    const int wm = wave >> 1, wn = wave & 1;
    const int row0 = blockIdx.y * 128, col0 = blockIdx.x * 128;

    floatx4 acc[4][4] = {};

    for (int k0 = 0; k0 < K; k0 += 64) {
        __syncthreads();
        #pragma unroll
        for (int j = 0; j < 4; ++j) {
            int chunk = tid + 256 * j;          // 1024 chunks of 8 bf16 = 8KB tile
            int r = chunk >> 3, c8 = (chunk & 7) * 8;
            uint4 va = *(const uint4*)(A  + (size_t)(row0 + r) * K + k0 + c8);
            *(uint4*)&Als[r][c8] = va;
            uint4 vb = *(const uint4*)(BT + (size_t)(col0 + r) * K + k0 + c8);
            *(uint4*)&Bls[r][c8] = vb;
        }
        __syncthreads();
        #pragma unroll
        for (int ks = 0; ks < 64; ks += 32) {
            frag8 af[4], bf[4];
            #pragma unroll
            for (int i = 0; i < 4; ++i)
                af[i] = *(const frag8*)&Als[wm * 64 + i * 16 + lrow][ks + quad * 8];
            #pragma unroll
            for (int i = 0; i < 4; ++i)
                bf[i] = *(const frag8*)&Bls[wn * 64 + i * 16 + lrow][ks + quad * 8];
            #pragma unroll
            for (int i = 0; i < 4; ++i)
                #pragma unroll
                for (int jn = 0; jn < 4; ++jn)
                    acc[i][jn] = __builtin_amdgcn_mfma_f32_16x16x32_bf16(
                        af[i], bf[jn], acc[i][jn], 0, 0, 0);
        }
    }

    // C/D layout (m89-verified): col = lane&15, row = quad*4 + reg
    #pragma unroll
    for (int i = 0; i < 4; ++i) {
        #pragma unroll
        for (int jn = 0; jn < 4; ++jn) {
            int col = col0 + wn * 64 + jn * 16 + lrow;
            bool isphi = col < phi_cols;
            #pragma unroll
            for (int r = 0; r < 4; ++r) {
                int row = row0 + wm * 64 + i * 16 + quad * 4 + r;
                float v = acc[i][jn][r];
                if (isphi) v = (v > 0.f) ? (v + 1.f) : __expf(v);  // phi = elu+1
                C[(size_t)row * N + col] = v;
            }
        }
    }
}

// ---------------------------------------------------------------------------
// Per-chunk local state: S_c = K_c^T V_c (64x64), z_c = sum_s k_s.
// ---------------------------------------------------------------------------
__global__ __launch_bounds__(256) void chunk_kv_k(
    const float* __restrict__ qkv,
    float* __restrict__ Sloc,
    float* __restrict__ zloc)
{
    __shared__ float Ks[64][64];
    __shared__ float Vs[64][64];
    const int blk = blockIdx.x;
    const int c = blk & 31, h = (blk >> 5) & 15, b = blk >> 9;
    const int t0 = c * 64;
    for (int e = threadIdx.x; e < 4096; e += 256) {
        int s = e >> 6, d = e & 63;
        size_t row = (size_t)(b * TB + t0 + s) * 3072;
        Ks[s][d] = qkv[row + 1024 + h * 64 + d];
        Vs[s][d] = qkv[row + 2048 + h * 64 + d];
    }
    __syncthreads();
    const int i = threadIdx.x >> 2;
    const int j0 = (threadIdx.x & 3) << 4;
    float acc[16] = {};
    for (int s = 0; s < 64; ++s) {
        float kv = Ks[s][i];
        #pragma unroll
        for (int j = 0; j < 16; ++j) acc[j] += kv * Vs[s][j0 + j];
    }
    float* So = Sloc + (size_t)blk * 4096;
    #pragma unroll
    for (int j = 0; j < 16; ++j) So[i * 64 + j0 + j] = acc[j];
    if (threadIdx.x < 64) {
        float z = 0.f;
        for (int s = 0; s < 64; ++s) z += Ks[s][threadIdx.x];
        zloc[(size_t)blk * 64 + threadIdx.x] = z;
    }
}

// ---------------------------------------------------------------------------
// Exclusive prefix over chunk axis, elementwise.
// ---------------------------------------------------------------------------
__global__ __launch_bounds__(256) void scan_state_k(
    float* __restrict__ S, float* __restrict__ z)
{
    const int bh = blockIdx.x >> 3;
    const int part = blockIdx.x & 7;
    const int e0 = part * 512 + threadIdx.x;
    const size_t base = (size_t)bh * NCH * 4096;
    float r0 = 0.f, r1 = 0.f;
    for (int c = 0; c < NCH; ++c) {
        float* Sc = S + base + (size_t)c * 4096;
        float t0 = Sc[e0];       Sc[e0] = r0;       r0 += t0;
        float t1 = Sc[e0 + 256]; Sc[e0 + 256] = r1; r1 += t1;
    }
    if (part == 0 && threadIdx.x < 64) {
        const size_t zb = (size_t)bh * NCH * 64;
        float rz = 0.f;
        for (int c = 0; c < NCH; ++c) {
            float t = z[zb + c * 64 + threadIdx.x];
            z[zb + c * 64 + threadIdx.x] = rz;
            rz += t;
        }
    }
}

// ---------------------------------------------------------------------------
// Per-chunk output, writes Y in bf16 (feeds MFMA GEMM2).
// ---------------------------------------------------------------------------
__global__ __launch_bounds__(256) void chunk_attn_k(
    const float* __restrict__ qkv,
    const float* __restrict__ Spref,
    const float* __restrict__ zpref,
    u16* __restrict__ Yb)
{
    __shared__ float Qs[64][64];
    __shared__ float Ps[64][65];   // reused: Sp, then K, then A
    __shared__ float Vs[64][64];
    __shared__ float zps[64];

    const int blk = blockIdx.x;
    const int c = blk & 31, h = (blk >> 5) & 15, b = blk >> 9;
    const int t0 = c * 64;
    const float* Sblk = Spref + (size_t)blk * 4096;

    for (int e = threadIdx.x; e < 4096; e += 256) {
        int s = e >> 6, d = e & 63;
        size_t row = (size_t)(b * TB + t0 + s) * 3072;
        Qs[s][d] = qkv[row + h * 64 + d];
        Vs[s][d] = qkv[row + 2048 + h * 64 + d];
        Ps[s][d] = Sblk[e];
    }
    if (threadIdx.x < 64) zps[threadIdx.x] = zpref[(size_t)blk * 64 + threadIdx.x];
    __syncthreads();

    const int t = threadIdx.x >> 2;
    const int j0 = (threadIdx.x & 3) << 4;

    float y[16] = {};
    float den = 0.f;
    for (int d = 0; d < 64; ++d) {
        float qd = Qs[t][d];
        den += qd * zps[d];
        #pragma unroll
        for (int j = 0; j < 16; ++j) y[j] += qd * Ps[d][j0 + j];
    }
    __syncthreads();

    for (int e = threadIdx.x; e < 4096; e += 256) {
        int s = e >> 6, d = e & 63;
        size_t row = (size_t)(b * TB + t0 + s) * 3072;
        Ps[s][d] = qkv[row + 1024 + h * 64 + d];
    }
    __syncthreads();

    float areg[16] = {};
    const int s0 = j0;
    for (int d = 0; d < 64; ++d) {
        float qd = Qs[t][d];
        #pragma unroll
        for (int j = 0; j < 16; ++j) areg[j] += qd * Ps[s0 + j][d];
    }
    #pragma unroll
    for (int j = 0; j < 16; ++j) if (s0 + j > t) areg[j] = 0.f;
    __syncthreads();

    #pragma unroll
    for (int j = 0; j < 16; ++j) Ps[t][s0 + j] = areg[j];
    __syncthreads();

    float rowsum = 0.f;
    for (int s = 0; s < 64; ++s) {
        float a = Ps[t][s];
        rowsum += a;
        #pragma unroll
        for (int j = 0; j < 16; ++j) y[j] += a * Vs[s][j0 + j];
    }
    den += rowsum;
    const float inv = 1.f / (den + EPSF);
    const size_t orow = (size_t)(b * TB + t0 + t) * CCH + h * 64 + j0;
    #pragma unroll
    for (int j = 0; j < 16; ++j) Yb[orow + j] = f2bf(y[j] * inv);
}

// ---------------------------------------------------------------------------
extern "C" void kernel_launch(void* const* d_in, const int* in_sizes, int n_in,
                              void* d_out, int out_size, void* d_ws, size_t ws_size,
                              hipStream_t stream)
{
    const float* x      = (const float*)d_in[0]; // (2,2048,1024) fp32
    const float* w_attn = (const float*)d_in[1]; // (1024,3072)   fp32
    const float* w_proj = (const float*)d_in[2]; // (1024,1024)   fp32
    float* out = (float*)d_out;                  // (2,2048,1024) fp32

    // Workspace layout:
    //   xb   : 4096*1024 bf16  (8 MB)
    //   waT  : 3072*1024 bf16  (6 MB)   w_attn^T
    //   wpT  : 1024*1024 bf16  (2 MB)   w_proj^T
    //   Yb   : 4096*1024 bf16  (8 MB)
    //   qkv  : 4096*3072 fp32  (48 MB)
    //   Sloc : 1024*4096 fp32  (16 MB)
    //   zloc : 1024*64   fp32  (0.25 MB)
    // total ~88.3 MB
    u16* xb   = (u16*)d_ws;
    u16* waT  = xb  + (size_t)4096 * 1024;
    u16* wpT  = waT + (size_t)3072 * 1024;
    u16* Yb   = wpT + (size_t)1024 * 1024;
    float* qkv  = (float*)(Yb + (size_t)4096 * 1024);
    float* Sloc = qkv  + (size_t)4096 * 3072;
    float* zloc = Sloc + (size_t)1024 * 4096;

    // Prep: convert x, transpose+convert weights
    cvt_bf16_k      <<<2048, 256, 0, stream>>>(x, xb, 4096 * 1024);
    transpose_bf16_k<<<dim3(48, 16), 256, 0, stream>>>(w_attn, waT, 1024, 3072);
    transpose_bf16_k<<<dim3(16, 16), 256, 0, stream>>>(w_proj, wpT, 1024, 1024);

    // GEMM1: qkv = phi(x @ w_attn) (phi on q,k thirds: cols < 2048)
    gemm_bf16_k<<<dim3(24, 32), 256, 0, stream>>>(xb, waT, qkv, 3072, 1024, 2048);

    // Chunked causal linear attention
    chunk_kv_k  <<<1024, 256, 0, stream>>>(qkv, Sloc, zloc);
    scan_state_k<<<256,  256, 0, stream>>>(Sloc, zloc);
    chunk_attn_k<<<1024, 256, 0, stream>>>(qkv, Sloc, zloc, Yb);

    // GEMM2: out = Y @ w_proj
    gemm_bf16_k<<<dim3(8, 32), 256, 0, stream>>>(Yb, wpT, out, 1024, 1024, 0);
}

// Round 5
// 181.021 us; speedup vs baseline: 5.1077x; 1.4555x over previous
//
#include <hip/hip_runtime.h>
#include <hip/hip_bf16.h>
#include <cmath>

// Problem dims (fixed by reference): B=2, T=2048, C=1024, H=16, D=64
// Inputs fp32, output fp32.
#define TB   2048
#define CCH  1024
#define NCH  32      // chunks per (b,h): T / 64
#define EPSF 1e-6f

typedef unsigned short u16;
typedef __attribute__((ext_vector_type(8))) short  frag8;   // 8 bf16 (4 VGPRs)
typedef __attribute__((ext_vector_type(4))) float  floatx4; // MFMA C/D

// RNE float -> bf16 (finite inputs only)
__device__ __forceinline__ u16 f2bf(float f) {
    unsigned int u = __float_as_uint(f);
    unsigned int r = (u + 0x7fffu + ((u >> 16) & 1u)) >> 16;
    return (u16)r;
}
__device__ __forceinline__ float bf2f(u16 v) {
    return __uint_as_float(((unsigned int)v) << 16);
}

// ---------------------------------------------------------------------------
// Convert fp32 -> bf16, 8 elems/thread.
// ---------------------------------------------------------------------------
__global__ __launch_bounds__(256) void cvt_bf16_k(
    const float* __restrict__ in, u16* __restrict__ out, int n)
{
    int i = (blockIdx.x * 256 + threadIdx.x) * 8;
    if (i >= n) return;
    float4 a = *(const float4*)(in + i);
    float4 b = *(const float4*)(in + i + 4);
    u16 v[8];
    v[0] = f2bf(a.x); v[1] = f2bf(a.y); v[2] = f2bf(a.z); v[3] = f2bf(a.w);
    v[4] = f2bf(b.x); v[5] = f2bf(b.y); v[6] = f2bf(b.z); v[7] = f2bf(b.w);
    *(uint4*)(out + i) = *(uint4*)v;
}

// ---------------------------------------------------------------------------
// Transpose + convert: in (K x N fp32, row-major) -> out (N x K bf16).
// ---------------------------------------------------------------------------
__global__ __launch_bounds__(256) void transpose_bf16_k(
    const float* __restrict__ in, u16* __restrict__ out, int K, int N)
{
    __shared__ u16 t[64][65];
    const int k0 = blockIdx.y * 64, n0 = blockIdx.x * 64;
    const int c = threadIdx.x & 63, r0 = threadIdx.x >> 6;
    for (int r = r0; r < 64; r += 4)
        t[c][r] = f2bf(in[(size_t)(k0 + r) * N + n0 + c]);
    __syncthreads();
    for (int r = r0; r < 64; r += 4)
        out[(size_t)(n0 + r) * K + k0 + c] = t[r][c];
}

// ---------------------------------------------------------------------------
// GEMM1: qkv(bf16) = phi(x @ w_attn). C bf16 out, phi on cols < phi_cols.
// 128x128 tile, BK=64, 4 waves x (4x4) 16x16x32 frags.
// ---------------------------------------------------------------------------
__global__ __launch_bounds__(256) void gemm_bf16_bf16out_k(
    const u16* __restrict__ A, const u16* __restrict__ BT,
    u16* __restrict__ C, int N, int K, int phi_cols)
{
    __shared__ u16 Als[128][72];
    __shared__ u16 Bls[128][72];
    const int tid  = threadIdx.x;
    const int wave = tid >> 6, lane = tid & 63;
    const int quad = lane >> 4, lrow = lane & 15;
    const int wm = wave >> 1, wn = wave & 1;
    const int row0 = blockIdx.y * 128, col0 = blockIdx.x * 128;

    floatx4 acc[4][4] = {};

    for (int k0 = 0; k0 < K; k0 += 64) {
        __syncthreads();
        #pragma unroll
        for (int j = 0; j < 4; ++j) {
            int chunk = tid + 256 * j;
            int r = chunk >> 3, c8 = (chunk & 7) * 8;
            *(uint4*)&Als[r][c8] = *(const uint4*)(A  + (size_t)(row0 + r) * K + k0 + c8);
            *(uint4*)&Bls[r][c8] = *(const uint4*)(BT + (size_t)(col0 + r) * K + k0 + c8);
        }
        __syncthreads();
        #pragma unroll
        for (int ks = 0; ks < 64; ks += 32) {
            frag8 af[4], bf[4];
            #pragma unroll
            for (int i = 0; i < 4; ++i)
                af[i] = *(const frag8*)&Als[wm * 64 + i * 16 + lrow][ks + quad * 8];
            #pragma unroll
            for (int i = 0; i < 4; ++i)
                bf[i] = *(const frag8*)&Bls[wn * 64 + i * 16 + lrow][ks + quad * 8];
            #pragma unroll
            for (int i = 0; i < 4; ++i)
                #pragma unroll
                for (int jn = 0; jn < 4; ++jn)
                    acc[i][jn] = __builtin_amdgcn_mfma_f32_16x16x32_bf16(
                        af[i], bf[jn], acc[i][jn], 0, 0, 0);
        }
    }

    #pragma unroll
    for (int i = 0; i < 4; ++i) {
        #pragma unroll
        for (int jn = 0; jn < 4; ++jn) {
            int col = col0 + wn * 64 + jn * 16 + lrow;
            bool isphi = col < phi_cols;
            #pragma unroll
            for (int r = 0; r < 4; ++r) {
                int row = row0 + wm * 64 + i * 16 + quad * 4 + r;
                float v = acc[i][jn][r];
                if (isphi) v = (v > 0.f) ? (v + 1.f) : __expf(v);  // phi = elu+1
                C[(size_t)row * N + col] = f2bf(v);
            }
        }
    }
}

// ---------------------------------------------------------------------------
// GEMM2: out(fp32) = Y @ w_proj. Same structure, fp32 epilogue.
// ---------------------------------------------------------------------------
__global__ __launch_bounds__(256) void gemm_bf16_f32out_k(
    const u16* __restrict__ A, const u16* __restrict__ BT,
    float* __restrict__ C, int N, int K)
{
    __shared__ u16 Als[128][72];
    __shared__ u16 Bls[128][72];
    const int tid  = threadIdx.x;
    const int wave = tid >> 6, lane = tid & 63;
    const int quad = lane >> 4, lrow = lane & 15;
    const int wm = wave >> 1, wn = wave & 1;
    const int row0 = blockIdx.y * 128, col0 = blockIdx.x * 128;

    floatx4 acc[4][4] = {};

    for (int k0 = 0; k0 < K; k0 += 64) {
        __syncthreads();
        #pragma unroll
        for (int j = 0; j < 4; ++j) {
            int chunk = tid + 256 * j;
            int r = chunk >> 3, c8 = (chunk & 7) * 8;
            *(uint4*)&Als[r][c8] = *(const uint4*)(A  + (size_t)(row0 + r) * K + k0 + c8);
            *(uint4*)&Bls[r][c8] = *(const uint4*)(BT + (size_t)(col0 + r) * K + k0 + c8);
        }
        __syncthreads();
        #pragma unroll
        for (int ks = 0; ks < 64; ks += 32) {
            frag8 af[4], bf[4];
            #pragma unroll
            for (int i = 0; i < 4; ++i)
                af[i] = *(const frag8*)&Als[wm * 64 + i * 16 + lrow][ks + quad * 8];
            #pragma unroll
            for (int i = 0; i < 4; ++i)
                bf[i] = *(const frag8*)&Bls[wn * 64 + i * 16 + lrow][ks + quad * 8];
            #pragma unroll
            for (int i = 0; i < 4; ++i)
                #pragma unroll
                for (int jn = 0; jn < 4; ++jn)
                    acc[i][jn] = __builtin_amdgcn_mfma_f32_16x16x32_bf16(
                        af[i], bf[jn], acc[i][jn], 0, 0, 0);
        }
    }

    #pragma unroll
    for (int i = 0; i < 4; ++i)
        #pragma unroll
        for (int jn = 0; jn < 4; ++jn) {
            int col = col0 + wn * 64 + jn * 16 + lrow;
            #pragma unroll
            for (int r = 0; r < 4; ++r) {
                int row = row0 + wm * 64 + i * 16 + quad * 4 + r;
                C[(size_t)row * N + col] = acc[i][jn][r];
            }
        }
}

// ---------------------------------------------------------------------------
// chunk_kv (MFMA): S_c^T = V^T K (64x64 fp32, stored [j][i]), z_c = rowsum K.
// Needs K^T, V^T ([feature][time]) in LDS -> transpose during staging.
// Grid 1024 blocks ((b*16+h)*32+c), 256 threads = 4 waves.
// ---------------------------------------------------------------------------
__global__ __launch_bounds__(256) void chunk_kv_mfma_k(
    const u16* __restrict__ qkv,
    float* __restrict__ Sloc,
    float* __restrict__ zloc)
{
    __shared__ u16 Kt[64][72];   // K^T [d][s]
    __shared__ u16 Vt[64][72];   // V^T [j][s]
    const int tid  = threadIdx.x;
    const int wave = tid >> 6, lane = tid & 63;
    const int quad = lane >> 4, lrow = lane & 15;
    const int blk = blockIdx.x;
    const int c = blk & 31, h = (blk >> 5) & 15, b = blk >> 9;
    const int t0 = c * 64;
    const u16* base = qkv + (size_t)(b * TB + t0) * 3072 + h * 64;

    #pragma unroll
    for (int m = 0; m < 2; ++m) {
        int chunk = tid + 256 * m;
        int s = chunk >> 3, d0 = (chunk & 7) * 8;
        const u16* row = base + (size_t)s * 3072;
        u16 kv[8], vv[8];
        *(uint4*)kv = *(const uint4*)(row + 1024 + d0);
        *(uint4*)vv = *(const uint4*)(row + 2048 + d0);
        #pragma unroll
        for (int q = 0; q < 8; ++q) { Kt[d0 + q][s] = kv[q]; Vt[d0 + q][s] = vv[q]; }
    }
    __syncthreads();

    // D[j][i] = sum_s V^T[j][s] K[s][i]  (A = Vt rows, B-operand = Kt rows)
    frag8 vf[2];
    #pragma unroll
    for (int ks = 0; ks < 2; ++ks)
        vf[ks] = *(const frag8*)&Vt[wave * 16 + lrow][ks * 32 + quad * 8];
    float* So = Sloc + (size_t)blk * 4096;
    #pragma unroll
    for (int jn = 0; jn < 4; ++jn) {
        floatx4 acc = {};
        #pragma unroll
        for (int ks = 0; ks < 2; ++ks) {
            frag8 kf = *(const frag8*)&Kt[jn * 16 + lrow][ks * 32 + quad * 8];
            acc = __builtin_amdgcn_mfma_f32_16x16x32_bf16(vf[ks], kf, acc, 0, 0, 0);
        }
        #pragma unroll
        for (int r = 0; r < 4; ++r) {
            int j = wave * 16 + quad * 4 + r;     // row of S^T
            int i = jn * 16 + lrow;               // col of S^T
            So[j * 64 + i] = acc[r];
        }
    }
    if (tid < 64) {
        float z = 0.f;
        for (int s = 0; s < 64; ++s) z += bf2f(Kt[tid][s]);
        zloc[(size_t)blk * 64 + tid] = z;
    }
}

// ---------------------------------------------------------------------------
// Exclusive prefix over chunk axis. Reads Sloc fp32, writes Spt bf16.
// Grid: 32 bh x 16 parts = 512 blocks.
// ---------------------------------------------------------------------------
__global__ __launch_bounds__(256) void scan_state_k(
    const float* __restrict__ Sloc, u16* __restrict__ Spt, float* __restrict__ z)
{
    const int bh = blockIdx.x >> 4;
    const int part = blockIdx.x & 15;
    const int e0 = part * 256 + threadIdx.x;
    const size_t base = (size_t)bh * NCH * 4096;
    float r = 0.f;
    for (int c = 0; c < NCH; ++c) {
        float t = Sloc[base + (size_t)c * 4096 + e0];
        Spt[base + (size_t)c * 4096 + e0] = f2bf(r);
        r += t;
    }
    if (part == 0 && threadIdx.x < 64) {
        const size_t zb = (size_t)bh * NCH * 64;
        float rz = 0.f;
        for (int c = 0; c < NCH; ++c) {
            float t = z[zb + c * 64 + threadIdx.x];
            z[zb + c * 64 + threadIdx.x] = rz;
            rz += t;
        }
    }
}

// ---------------------------------------------------------------------------
// attn (MFMA): y = (Q*Sp^T + causal(QK^T)*V) / (q.zp + rowsum + eps), bf16 out.
// Grid 1024 blocks, 256 threads = 4 waves; wave w owns t-rows [16w,16w+16).
// ---------------------------------------------------------------------------
__global__ __launch_bounds__(256) void attn_mfma_k(
    const u16* __restrict__ qkv,
    const u16* __restrict__ SptG,
    const float* __restrict__ zp,
    u16* __restrict__ Yb)
{
    __shared__ u16 Qs[64][72];   // Q natural [t][d]; reused as Y staging
    __shared__ u16 Ks[64][72];   // K natural [s][d]
    __shared__ u16 Vt[64][72];   // V^T [j][s]
    __shared__ u16 Sp[64][72];   // S_pref^T [j][d]
    __shared__ u16 As[64][72];   // masked A [t][s] bf16
    __shared__ float zps[64];
    __shared__ float den4[64][4];
    __shared__ float den[64];

    const int tid  = threadIdx.x;
    const int wave = tid >> 6, lane = tid & 63;
    const int quad = lane >> 4, lrow = lane & 15;
    const int blk = blockIdx.x;
    const int c = blk & 31, h = (blk >> 5) & 15, b = blk >> 9;
    const int t0 = c * 64;
    const u16* base = qkv + (size_t)(b * TB + t0) * 3072 + h * 64;

    #pragma unroll
    for (int m = 0; m < 2; ++m) {
        int chunk = tid + 256 * m;
        int s = chunk >> 3, d0 = (chunk & 7) * 8;
        const u16* row = base + (size_t)s * 3072;
        *(uint4*)&Qs[s][d0] = *(const uint4*)(row + d0);
        *(uint4*)&Ks[s][d0] = *(const uint4*)(row + 1024 + d0);
        u16 vv[8];
        *(uint4*)vv = *(const uint4*)(row + 2048 + d0);
        #pragma unroll
        for (int q = 0; q < 8; ++q) Vt[d0 + q][s] = vv[q];
        *(uint4*)&Sp[s][d0] = *(const uint4*)(SptG + (size_t)blk * 4096 + chunk * 8);
    }
    if (tid < 64) zps[tid] = zp[(size_t)blk * 64 + tid];
    __syncthreads();

    frag8 qf[2];
    #pragma unroll
    for (int ks = 0; ks < 2; ++ks)
        qf[ks] = *(const frag8*)&Qs[wave * 16 + lrow][ks * 32 + quad * 8];

    floatx4 yacc[4] = {}, kacc[4] = {};
    #pragma unroll
    for (int jn = 0; jn < 4; ++jn) {
        #pragma unroll
        for (int ks = 0; ks < 2; ++ks) {
            frag8 spf = *(const frag8*)&Sp[jn * 16 + lrow][ks * 32 + quad * 8];
            yacc[jn] = __builtin_amdgcn_mfma_f32_16x16x32_bf16(qf[ks], spf, yacc[jn], 0, 0, 0);
            frag8 kf = *(const frag8*)&Ks[jn * 16 + lrow][ks * 32 + quad * 8];
            kacc[jn] = __builtin_amdgcn_mfma_f32_16x16x32_bf16(qf[ks], kf, kacc[jn], 0, 0, 0);
        }
    }

    // mask + store A (bf16) to LDS [t][s]
    #pragma unroll
    for (int jn = 0; jn < 4; ++jn) {
        int s = jn * 16 + lrow;
        #pragma unroll
        for (int r = 0; r < 4; ++r) {
            int t = wave * 16 + quad * 4 + r;
            float v = (s <= t) ? kacc[jn][r] : 0.f;
            As[t][s] = f2bf(v);
        }
    }
    __syncthreads();

    // den partials: den[t] = sum_d Q[t][d]*zp[d] + sum_s As[t][s]
    {
        int t = tid >> 2, seg = tid & 3;
        float p = 0.f;
        #pragma unroll
        for (int i = 0; i < 16; ++i) {
            int d = seg * 16 + i;
            p += bf2f(Qs[t][d]) * zps[d] + bf2f(As[t][d]);
        }
        den4[t][seg] = p;
    }

    // y += A @ V
    frag8 af2[2];
    #pragma unroll
    for (int ks = 0; ks < 2; ++ks)
        af2[ks] = *(const frag8*)&As[wave * 16 + lrow][ks * 32 + quad * 8];
    #pragma unroll
    for (int jn = 0; jn < 4; ++jn)
        #pragma unroll
        for (int ks = 0; ks < 2; ++ks) {
            frag8 vf = *(const frag8*)&Vt[jn * 16 + lrow][ks * 32 + quad * 8];
            yacc[jn] = __builtin_amdgcn_mfma_f32_16x16x32_bf16(af2[ks], vf, yacc[jn], 0, 0, 0);
        }
    __syncthreads();
    if (tid < 64) den[tid] = den4[tid][0] + den4[tid][1] + den4[tid][2] + den4[tid][3];
    __syncthreads();

    // epilogue: normalize, stage into Qs (reused), then vectorized store
    #pragma unroll
    for (int jn = 0; jn < 4; ++jn) {
        #pragma unroll
        for (int r = 0; r < 4; ++r) {
            int t = wave * 16 + quad * 4 + r;
            float inv = 1.f / (den[t] + EPSF);
            Qs[t][jn * 16 + lrow] = f2bf(yacc[jn][r] * inv);
        }
    }
    __syncthreads();
    {
        int row = tid >> 2, seg = tid & 3;
        size_t o = (size_t)(b * TB + t0 + row) * CCH + h * 64 + seg * 16;
        *(uint4*)(Yb + o)     = *(uint4*)&Qs[row][seg * 16];
        *(uint4*)(Yb + o + 8) = *(uint4*)&Qs[row][seg * 16 + 8];
    }
}

// ---------------------------------------------------------------------------
extern "C" void kernel_launch(void* const* d_in, const int* in_sizes, int n_in,
                              void* d_out, int out_size, void* d_ws, size_t ws_size,
                              hipStream_t stream)
{
    const float* x      = (const float*)d_in[0]; // (2,2048,1024) fp32
    const float* w_attn = (const float*)d_in[1]; // (1024,3072)   fp32
    const float* w_proj = (const float*)d_in[2]; // (1024,1024)   fp32
    float* out = (float*)d_out;                  // (2,2048,1024) fp32

    // Workspace layout:
    //   xb    : 4096*1024 bf16  (8 MB)
    //   waT   : 3072*1024 bf16  (6 MB)
    //   wpT   : 1024*1024 bf16  (2 MB)
    //   Yb    : 4096*1024 bf16  (8 MB)
    //   qkv_b : 4096*3072 bf16  (24 MB)
    //   Spt   : 1024*4096 bf16  (8 MB)
    //   Sloc  : 1024*4096 fp32  (16 MB)
    //   zloc  : 1024*64   fp32  (0.25 MB)
    // total ~72.3 MB
    u16* xb    = (u16*)d_ws;
    u16* waT   = xb   + (size_t)4096 * 1024;
    u16* wpT   = waT  + (size_t)3072 * 1024;
    u16* Yb    = wpT  + (size_t)1024 * 1024;
    u16* qkv_b = Yb   + (size_t)4096 * 1024;
    u16* Spt   = qkv_b + (size_t)4096 * 3072;
    float* Sloc = (float*)(Spt + (size_t)1024 * 4096);
    float* zloc = Sloc + (size_t)1024 * 4096;

    cvt_bf16_k      <<<2048, 256, 0, stream>>>(x, xb, 4096 * 1024);
    transpose_bf16_k<<<dim3(48, 16), 256, 0, stream>>>(w_attn, waT, 1024, 3072);
    transpose_bf16_k<<<dim3(16, 16), 256, 0, stream>>>(w_proj, wpT, 1024, 1024);

    // GEMM1: qkv(bf16) = phi(x @ w_attn) (phi on q,k thirds: cols < 2048)
    gemm_bf16_bf16out_k<<<dim3(24, 32), 256, 0, stream>>>(xb, waT, qkv_b, 3072, 1024, 2048);

    // Chunked causal linear attention (all MFMA)
    chunk_kv_mfma_k<<<1024, 256, 0, stream>>>(qkv_b, Sloc, zloc);
    scan_state_k   <<<512,  256, 0, stream>>>(Sloc, Spt, zloc);
    attn_mfma_k    <<<1024, 256, 0, stream>>>(qkv_b, Spt, zloc, Yb);

    // GEMM2: out = Y @ w_proj
    gemm_bf16_f32out_k<<<dim3(8, 32), 256, 0, stream>>>(Yb, wpT, out, 1024, 1024);
}